// Round 1
// baseline (1306.010 us; speedup 1.0000x reference)
//
#include <hip/hip_runtime.h>

typedef __bf16 bf16;
typedef __attribute__((ext_vector_type(8))) __bf16 bf16x8;
typedef __attribute__((ext_vector_type(4))) float f32x4;

constexpr int Bb = 4, S = 2048, Dd = 2048, H = 16, G = 4, HD = 128;
constexpr float L2E = 1.4426950408889634f;

__device__ inline f32x4 mfma16(bf16x8 a, bf16x8 b, f32x4 c) {
  return __builtin_amdgcn_mfma_f32_16x16x32_bf16(a, b, c, 0, 0, 0);
}

__device__ inline void gl_lds16(const void* g, void* l) {
  __builtin_amdgcn_global_load_lds(
      (const __attribute__((address_space(1))) void*)g,
      (__attribute__((address_space(3))) void*)l, 16, 0, 0);
}

// ---------------- fp32 -> bf16 elementwise (vectorized) ----------------
__global__ __launch_bounds__(256) void k_f32_to_bf16(
    const float* __restrict__ in, bf16* __restrict__ out, int n8) {
  int i = blockIdx.x * 256 + threadIdx.x;
  if (i >= n8) return;
  const float4* p = (const float4*)(in + (long long)i * 8);
  float4 a = p[0], b = p[1];
  bf16x8 v;
  v[0] = (bf16)a.x; v[1] = (bf16)a.y; v[2] = (bf16)a.z; v[3] = (bf16)a.w;
  v[4] = (bf16)b.x; v[5] = (bf16)b.y; v[6] = (bf16)b.z; v[7] = (bf16)b.w;
  *(bf16x8*)(out + (long long)i * 8) = v;
}

// ---------------- transpose + convert to bf16 ----------------
// out[c][r] = (bf16) in[r][c];  batch z: in offset (z/nb2)*s1 + (z%nb2)*s2
template <typename InT>
__global__ __launch_bounds__(256) void k_transpose_bf16(
    const InT* __restrict__ in, long long s1, int nb2, long long s2, int ldin,
    bf16* __restrict__ out, long long obatch, int ldout, int R, int C) {
  __shared__ float tile[32][33];
  int z = blockIdx.z;
  const InT* ip = in + (long long)(z / nb2) * s1 + (long long)(z % nb2) * s2;
  bf16* op = out + (long long)z * obatch;
  int c0 = blockIdx.x * 32, r0 = blockIdx.y * 32;
  int tx = threadIdx.x, ty = threadIdx.y;
#pragma unroll
  for (int i = 0; i < 4; ++i) {
    int r = r0 + ty + i * 8, c = c0 + tx;
    tile[ty + i * 8][tx] = (r < R && c < C) ? (float)ip[(long long)r * ldin + c] : 0.f;
  }
  __syncthreads();
#pragma unroll
  for (int i = 0; i < 4; ++i) {
    int c = c0 + ty + i * 8, r = r0 + tx;
    if (c < C && r < R) op[(long long)c * ldout + r] = (bf16)tile[tx][ty + i * 8];
  }
}

// ---------------- bf16 GEMM:  C(MxN) = A(MxK) * Bt(NxK)^T ----------------
// m97-style: 128x128 tile, BK=32, 4 waves, global_load_lds width 16.
template <typename CT>
__global__ __launch_bounds__(256) void k_gemm_bt(
    const bf16* __restrict__ A, int lda, const bf16* __restrict__ Bt, int ldb,
    CT* __restrict__ C, int ldc, int M, int N, int K) {
  __shared__ bf16 As[128][32];
  __shared__ bf16 Bs[128][32];
  const int tid = threadIdx.x;
  const int w = tid >> 6, lane = tid & 63;
  const int l16 = lane & 15, lh = lane >> 4;
  const int nbn = N >> 7;
  const int bm = blockIdx.x / nbn, bn = blockIdx.x % nbn;
  const int m0 = bm << 7, n0 = bn << 7;
  const int wm = (w >> 1) << 6, wn = (w & 1) << 6;
  const int ar = tid >> 2;          // 0..63
  const int ac = (tid & 3) * 8;
  f32x4 acc[4][4] = {};
  for (int k0 = 0; k0 < K; k0 += 32) {
    __syncthreads();
#pragma unroll
    for (int p = 0; p < 2; ++p) {
      gl_lds16(A + (long long)(m0 + p * 64 + ar) * lda + k0 + ac,
               (char*)&As[0][0] + p * 4096 + w * 1024);
      gl_lds16(Bt + (long long)(n0 + p * 64 + ar) * ldb + k0 + ac,
               (char*)&Bs[0][0] + p * 4096 + w * 1024);
    }
    __syncthreads();
    bf16x8 af[4], bfv[4];
#pragma unroll
    for (int i = 0; i < 4; ++i) af[i] = *(const bf16x8*)&As[wm + i * 16 + l16][lh * 8];
#pragma unroll
    for (int j = 0; j < 4; ++j) bfv[j] = *(const bf16x8*)&Bs[wn + j * 16 + l16][lh * 8];
#pragma unroll
    for (int i = 0; i < 4; ++i)
#pragma unroll
      for (int j = 0; j < 4; ++j) acc[i][j] = mfma16(af[i], bfv[j], acc[i][j]);
  }
#pragma unroll
  for (int i = 0; i < 4; ++i)
#pragma unroll
    for (int j = 0; j < 4; ++j)
#pragma unroll
      for (int r = 0; r < 4; ++r)
        C[(long long)(m0 + wm + i * 16 + lh * 4 + r) * ldc + n0 + wn + j * 16 + l16] =
            (CT)acc[i][j][r];
}

// ---------------- RMSNorm + RoPE (wave per (b,s,h) row) ----------------
__global__ __launch_bounds__(256) void k_rms_rope(
    const bf16* __restrict__ in, int ldin, int nh, const float* __restrict__ scale,
    const float* __restrict__ cosT, const float* __restrict__ sinT,
    bf16* __restrict__ out, float oscale, int nwaves) {
  int wid = (blockIdx.x * 256 + threadIdx.x) >> 6;
  if (wid >= nwaves) return;
  int lane = threadIdx.x & 63;
  int h = wid % nh;
  int bs = wid / nh;
  int s = bs % S;
  int b = bs / S;
  const bf16* ip = in + (long long)bs * ldin + h * HD;
  float x1 = (float)ip[lane], x2 = (float)ip[lane + 64];
  float ss = x1 * x1 + x2 * x2;
#pragma unroll
  for (int m = 1; m < 64; m <<= 1) ss += __shfl_xor(ss, m);
  float rms = rsqrtf(ss * (1.f / 128.f) + 1e-6f);
  float n1 = x1 * rms * (1.f + scale[lane]);
  float n2 = x2 * rms * (1.f + scale[lane + 64]);
  float o1 = (n1 * cosT[s * 128 + lane] - n2 * sinT[s * 128 + lane]) * oscale;
  float o2 = (n2 * cosT[s * 128 + lane + 64] + n1 * sinT[s * 128 + lane + 64]) * oscale;
  bf16* op = out + (((long long)b * nh + h) * S + s) * HD;
  op[lane] = (bf16)o1;
  op[lane + 64] = (bf16)o2;
}

// ---------------- sigmoid in-place on strided bf16 slice ----------------
__global__ __launch_bounds__(256) void k_sigmoid(bf16* __restrict__ p, int ld,
                                                 int cols8, int n) {
  int i = blockIdx.x * 256 + threadIdx.x;
  if (i >= n) return;
  int row = i / cols8, c = (i % cols8) * 8;
  bf16x8* q = (bf16x8*)(p + (long long)row * ld + c);
  bf16x8 v = *q;
#pragma unroll
  for (int j = 0; j < 8; ++j) {
    float f = (float)v[j];
    v[j] = (bf16)(1.f / (1.f + exp2f(-f * L2E)));
  }
  *q = v;
}

// ---------------- causal GQA flash attention ----------------
// Q:(B,H,S,128) pre-scaled by 1/sqrt(128); K:(B,G,S,128); Vt:(B,G,128,S)
// out = softmax(QK^T masked) V * gate, written bf16 to ctxg (strided).
__global__ __launch_bounds__(256) void k_flash(
    const bf16* __restrict__ Q, const bf16* __restrict__ Kb,
    const bf16* __restrict__ Vt, const bf16* __restrict__ gate, int ldg,
    bf16* __restrict__ outc, int ldo) {
  __shared__ bf16 Plds[4][16][40];  // pitch 40 bf16 = 80B (16B aligned, conflict-lite)
  const int tid = threadIdx.x, w = tid >> 6, lane = tid & 63;
  const int l16 = lane & 15, lh = lane >> 4;
  const int qt = blockIdx.x & 31;
  const int bh = blockIdx.x >> 5;
  const int h = bh & 15, b = bh >> 4;
  const int g = h >> 2;
  const int q0 = qt * 64 + w * 16;
  const bf16* qp = Q + (((long long)b * H + h) * S + q0) * HD;
  const bf16* kp = Kb + ((long long)b * G + g) * S * HD;
  const bf16* vp = Vt + ((long long)b * G + g) * HD * S;
  bf16x8 aq[4];
#pragma unroll
  for (int i = 0; i < 4; ++i)
    aq[i] = *(const bf16x8*)(qp + (long long)l16 * HD + i * 32 + lh * 8);
  f32x4 acc[8] = {};
  float mrow[4] = {-1e30f, -1e30f, -1e30f, -1e30f};
  float lrow[4] = {0.f, 0.f, 0.f, 0.f};
  const int tmax = (q0 + 15) >> 5;
  for (int t = 0; t <= tmax; ++t) {
    const int kv0 = t << 5;
    f32x4 s0 = {0.f, 0.f, 0.f, 0.f}, s1 = {0.f, 0.f, 0.f, 0.f};
    const bf16* kb = kp + (long long)(kv0 + l16) * HD + lh * 8;
#pragma unroll
    for (int ks = 0; ks < 4; ++ks) {
      bf16x8 b0 = *(const bf16x8*)(kb + ks * 32);
      bf16x8 b1 = *(const bf16x8*)(kb + 16 * HD + ks * 32);
      s0 = mfma16(aq[ks], b0, s0);
      s1 = mfma16(aq[ks], b1, s1);
    }
    if (kv0 + 31 > q0) {
#pragma unroll
      for (int r = 0; r < 4; ++r) {
        int gr = q0 + lh * 4 + r;
        if (kv0 + l16 > gr) s0[r] = -1e30f;
        if (kv0 + 16 + l16 > gr) s1[r] = -1e30f;
      }
    }
    float pm[4];
#pragma unroll
    for (int r = 0; r < 4; ++r) pm[r] = fmaxf(s0[r], s1[r]);
#pragma unroll
    for (int m = 1; m < 16; m <<= 1)
#pragma unroll
      for (int r = 0; r < 4; ++r) pm[r] = fmaxf(pm[r], __shfl_xor(pm[r], m));
    float resc[4];
#pragma unroll
    for (int r = 0; r < 4; ++r) {
      float mn = fmaxf(mrow[r], pm[r]);
      resc[r] = exp2f((mrow[r] - mn) * L2E);
      mrow[r] = mn;
    }
#pragma unroll
    for (int r = 0; r < 4; ++r) {
      float p0 = exp2f((s0[r] - mrow[r]) * L2E);
      float p1 = exp2f((s1[r] - mrow[r]) * L2E);
      lrow[r] = lrow[r] * resc[r] + p0 + p1;  // per-lane partial row sum (2 cols)
      Plds[w][lh * 4 + r][l16] = (bf16)p0;
      Plds[w][lh * 4 + r][16 + l16] = (bf16)p1;
    }
#pragma unroll
    for (int dt = 0; dt < 8; ++dt)
#pragma unroll
      for (int r = 0; r < 4; ++r) acc[dt][r] *= resc[r];
    bf16x8 pa = *(const bf16x8*)&Plds[w][l16][lh * 8];
    const bf16* vb = vp + (long long)l16 * S + kv0 + lh * 8;
#pragma unroll
    for (int dt = 0; dt < 8; ++dt) {
      bf16x8 bv = *(const bf16x8*)(vb + (long long)dt * 16 * S);
      acc[dt] = mfma16(pa, bv, acc[dt]);
    }
  }
#pragma unroll
  for (int m = 1; m < 16; m <<= 1)
#pragma unroll
    for (int r = 0; r < 4; ++r) lrow[r] += __shfl_xor(lrow[r], m);
  float inv[4];
#pragma unroll
  for (int r = 0; r < 4; ++r) inv[r] = 1.f / lrow[r];
#pragma unroll
  for (int dt = 0; dt < 8; ++dt)
#pragma unroll
    for (int r = 0; r < 4; ++r) {
      int gr = q0 + lh * 4 + r;
      long long row = (long long)b * S + gr;
      int col = h * HD + dt * 16 + l16;
      float gv = (float)gate[row * ldg + col];
      outc[row * ldo + col] = (bf16)(acc[dt][r] * inv[r] * gv);
    }
}

extern "C" void kernel_launch(void* const* d_in, const int* in_sizes, int n_in,
                              void* d_out, int out_size, void* d_ws, size_t ws_size,
                              hipStream_t stream) {
  const float* x = (const float*)d_in[0];
  // d_in[1] = mask (causal tril) — recomputed analytically, unused
  const float* cosT = (const float*)d_in[2];
  const float* sinT = (const float*)d_in[3];
  const float* wq = (const float*)d_in[4];
  const float* wk = (const float*)d_in[5];
  const float* wv = (const float*)d_in[6];
  const float* wg = (const float*)d_in[7];
  const float* wo = (const float*)d_in[8];
  const float* qs = (const float*)d_in[9];
  const float* ksc = (const float*)d_in[10];
  float* out = (float*)d_out;
  char* ws = (char*)d_ws;

  // workspace layout (bytes), with deliberate aliasing:
  //   [0,        33.5MB) x_bf16   -> reused as q (B,H,S,128) after GEMM1
  //   [33.5MB,   54.5MB) wcat^T   -> reused as k (B,G,S,128) + vT (B,G,128,S)
  //   [54.5MB,   62.9MB) wo^T
  //   [62.9MB,  146.8MB) C1 (8192x5120 bf16): qkvg GEMM out; gate in-place at
  //                      col 3072; ctx*gate written over cols 0:2048
  if (ws_size < 146800640) return;  // insufficient scratch — fail visibly
  bf16* xb = (bf16*)(ws);
  bf16* wcat = (bf16*)(ws + 33554432);
  bf16* woT = (bf16*)(ws + 54525952);
  bf16* C1 = (bf16*)(ws + 62914560);
  bf16* qbuf = xb;
  bf16* kbuf = wcat;
  bf16* vtbuf = wcat + 4194304;
  bf16* gatep = C1 + 3072;
  bf16* ctxg = C1;

  dim3 tb(32, 8);
  // 1. x -> bf16
  k_f32_to_bf16<<<8192, 256, 0, stream>>>(x, xb, Bb * S * Dd / 8);
  // 2. weights -> transposed bf16 (concatenated wq|wk|wv|wg rows)
  k_transpose_bf16<float><<<dim3(64, 64, 1), tb, 0, stream>>>(
      wq, 0, 1, 0, 2048, wcat, 0, 2048, 2048, 2048);
  k_transpose_bf16<float><<<dim3(16, 64, 1), tb, 0, stream>>>(
      wk, 0, 1, 0, 512, wcat + 2048 * 2048, 0, 2048, 2048, 512);
  k_transpose_bf16<float><<<dim3(16, 64, 1), tb, 0, stream>>>(
      wv, 0, 1, 0, 512, wcat + 2560 * 2048, 0, 2048, 2048, 512);
  k_transpose_bf16<float><<<dim3(64, 64, 1), tb, 0, stream>>>(
      wg, 0, 1, 0, 2048, wcat + 3072 * 2048, 0, 2048, 2048, 2048);
  k_transpose_bf16<float><<<dim3(64, 64, 1), tb, 0, stream>>>(
      wo, 0, 1, 0, 2048, woT, 0, 2048, 2048, 2048);
  // 3. fused QKVG GEMM: (8192x2048) @ (2048x5120) -> C1 bf16
  k_gemm_bt<bf16><<<64 * 40, 256, 0, stream>>>(xb, 2048, wcat, 2048, C1, 5120,
                                               8192, 5120, 2048);
  // 4. RMSNorm + RoPE; 1/sqrt(128) folded into q
  k_rms_rope<<<32768, 256, 0, stream>>>(C1, 5120, 16, qs, cosT, sinT, qbuf,
                                        0.08838834764831845f, 131072);
  k_rms_rope<<<8192, 256, 0, stream>>>(C1 + 2048, 5120, 4, ksc, cosT, sinT, kbuf,
                                       1.0f, 32768);
  // 5. V -> V^T (B,G,128,S)
  k_transpose_bf16<bf16><<<dim3(4, 64, 16), tb, 0, stream>>>(
      C1 + 2560, (long long)2048 * 5120, 4, 128, 5120, vtbuf,
      (long long)128 * 2048, 2048, 2048, 128);
  // 6. gate = sigmoid(xwg) in-place in C1
  k_sigmoid<<<8192, 256, 0, stream>>>(gatep, 5120, 256, 2097152);
  // 7. flash attention + gate, ctx*gate -> C1 cols 0:2048
  k_flash<<<2048, 256, 0, stream>>>(qbuf, kbuf, vtbuf, gatep, 5120, ctxg, 5120);
  // 8. output GEMM: (8192x2048) @ (2048x2048) -> out fp32
  k_gemm_bt<float><<<64 * 16, 256, 0, stream>>>(ctxg, 5120, woT, 2048, out, 2048,
                                                8192, 2048, 2048);
}

// Round 2
// 589.353 us; speedup vs baseline: 2.2160x; 2.2160x over previous
//
#include <hip/hip_runtime.h>

typedef __bf16 bf16;
typedef __attribute__((ext_vector_type(8))) __bf16 bf16x8;
typedef __attribute__((ext_vector_type(4))) float f32x4;

constexpr int Bb = 4, S = 2048, Dd = 2048, H = 16, G = 4, HD = 128;
constexpr float L2E = 1.4426950408889634f;

__device__ inline f32x4 mfma16(bf16x8 a, bf16x8 b, f32x4 c) {
  return __builtin_amdgcn_mfma_f32_16x16x32_bf16(a, b, c, 0, 0, 0);
}

__device__ inline void gl_lds16(const void* g, void* l) {
  __builtin_amdgcn_global_load_lds(
      (const __attribute__((address_space(1))) void*)g,
      (__attribute__((address_space(3))) void*)l, 16, 0, 0);
}

// ---------------- fp32 -> bf16 elementwise (vectorized) ----------------
__global__ __launch_bounds__(256) void k_f32_to_bf16(
    const float* __restrict__ in, bf16* __restrict__ out, int n8) {
  int i = blockIdx.x * 256 + threadIdx.x;
  if (i >= n8) return;
  const float4* p = (const float4*)(in + (long long)i * 8);
  float4 a = p[0], b = p[1];
  bf16x8 v;
  v[0] = (bf16)a.x; v[1] = (bf16)a.y; v[2] = (bf16)a.z; v[3] = (bf16)a.w;
  v[4] = (bf16)b.x; v[5] = (bf16)b.y; v[6] = (bf16)b.z; v[7] = (bf16)b.w;
  *(bf16x8*)(out + (long long)i * 8) = v;
}

// ---------------- transpose + convert to bf16 ----------------
template <typename InT>
__global__ __launch_bounds__(256) void k_transpose_bf16(
    const InT* __restrict__ in, long long s1, int nb2, long long s2, int ldin,
    bf16* __restrict__ out, long long obatch, int ldout, int R, int C) {
  __shared__ float tile[32][33];
  int z = blockIdx.z;
  const InT* ip = in + (long long)(z / nb2) * s1 + (long long)(z % nb2) * s2;
  bf16* op = out + (long long)z * obatch;
  int c0 = blockIdx.x * 32, r0 = blockIdx.y * 32;
  int tx = threadIdx.x, ty = threadIdx.y;
#pragma unroll
  for (int i = 0; i < 4; ++i) {
    int r = r0 + ty + i * 8, c = c0 + tx;
    tile[ty + i * 8][tx] = (r < R && c < C) ? (float)ip[(long long)r * ldin + c] : 0.f;
  }
  __syncthreads();
#pragma unroll
  for (int i = 0; i < 4; ++i) {
    int c = c0 + ty + i * 8, r = r0 + tx;
    if (c < C && r < R) op[(long long)c * ldout + r] = (bf16)tile[tx][ty + i * 8];
  }
}

// ---------------- bf16 GEMM:  C(MxN) = A(MxK) * Bt(NxK)^T ----------------
template <typename CT>
__global__ __launch_bounds__(256) void k_gemm_bt(
    const bf16* __restrict__ A, int lda, const bf16* __restrict__ Bt, int ldb,
    CT* __restrict__ C, int ldc, int M, int N, int K) {
  __shared__ bf16 As[128][32];
  __shared__ bf16 Bs[128][32];
  const int tid = threadIdx.x;
  const int w = tid >> 6, lane = tid & 63;
  const int l16 = lane & 15, lh = lane >> 4;
  const int nbn = N >> 7;
  const int bm = blockIdx.x / nbn, bn = blockIdx.x % nbn;
  const int m0 = bm << 7, n0 = bn << 7;
  const int wm = (w >> 1) << 6, wn = (w & 1) << 6;
  const int ar = tid >> 2;
  const int ac = (tid & 3) * 8;
  f32x4 acc[4][4] = {};
  for (int k0 = 0; k0 < K; k0 += 32) {
    __syncthreads();
#pragma unroll
    for (int p = 0; p < 2; ++p) {
      gl_lds16(A + (long long)(m0 + p * 64 + ar) * lda + k0 + ac,
               (char*)&As[0][0] + p * 4096 + w * 1024);
      gl_lds16(Bt + (long long)(n0 + p * 64 + ar) * ldb + k0 + ac,
               (char*)&Bs[0][0] + p * 4096 + w * 1024);
    }
    __syncthreads();
    bf16x8 af[4], bfv[4];
#pragma unroll
    for (int i = 0; i < 4; ++i) af[i] = *(const bf16x8*)&As[wm + i * 16 + l16][lh * 8];
#pragma unroll
    for (int j = 0; j < 4; ++j) bfv[j] = *(const bf16x8*)&Bs[wn + j * 16 + l16][lh * 8];
#pragma unroll
    for (int i = 0; i < 4; ++i)
#pragma unroll
      for (int j = 0; j < 4; ++j) acc[i][j] = mfma16(af[i], bfv[j], acc[i][j]);
  }
#pragma unroll
  for (int i = 0; i < 4; ++i)
#pragma unroll
    for (int j = 0; j < 4; ++j)
#pragma unroll
      for (int r = 0; r < 4; ++r)
        C[(long long)(m0 + wm + i * 16 + lh * 4 + r) * ldc + n0 + wn + j * 16 + l16] =
            (CT)acc[i][j][r];
}

// ---------------- RMSNorm + RoPE (wave per (b,s,h) row) ----------------
__global__ __launch_bounds__(256) void k_rms_rope(
    const bf16* __restrict__ in, int ldin, int nh, const float* __restrict__ scale,
    const float* __restrict__ cosT, const float* __restrict__ sinT,
    bf16* __restrict__ out, float oscale, int nwaves) {
  int wid = (blockIdx.x * 256 + threadIdx.x) >> 6;
  if (wid >= nwaves) return;
  int lane = threadIdx.x & 63;
  int h = wid % nh;
  int bs = wid / nh;
  int s = bs % S;
  int b = bs / S;
  const bf16* ip = in + (long long)bs * ldin + h * HD;
  float x1 = (float)ip[lane], x2 = (float)ip[lane + 64];
  float ss = x1 * x1 + x2 * x2;
#pragma unroll
  for (int m = 1; m < 64; m <<= 1) ss += __shfl_xor(ss, m);
  float rms = rsqrtf(ss * (1.f / 128.f) + 1e-6f);
  float n1 = x1 * rms * (1.f + scale[lane]);
  float n2 = x2 * rms * (1.f + scale[lane + 64]);
  float o1 = (n1 * cosT[s * 128 + lane] - n2 * sinT[s * 128 + lane]) * oscale;
  float o2 = (n2 * cosT[s * 128 + lane + 64] + n1 * sinT[s * 128 + lane + 64]) * oscale;
  bf16* op = out + (((long long)b * nh + h) * S + s) * HD;
  op[lane] = (bf16)o1;
  op[lane + 64] = (bf16)o2;
}

// ---------------- sigmoid in-place on strided bf16 slice ----------------
__global__ __launch_bounds__(256) void k_sigmoid(bf16* __restrict__ p, int ld,
                                                 int cols8, int n) {
  int i = blockIdx.x * 256 + threadIdx.x;
  if (i >= n) return;
  int row = i / cols8, c = (i % cols8) * 8;
  bf16x8* q = (bf16x8*)(p + (long long)row * ld + c);
  bf16x8 v = *q;
#pragma unroll
  for (int j = 0; j < 8; ++j) {
    float f = (float)v[j];
    v[j] = (bf16)(1.f / (1.f + exp2f(-f * L2E)));
  }
  *q = v;
}

// ---------------- causal GQA flash attention v2 ----------------
// 8 waves x 32 Q rows = 256 Q rows/block. KV tiles of 64 double-buffered in
// LDS (XOR-swizzled, staged via global_load_lds with pre-swizzled source).
// Q pre-scaled by L2E/sqrt(HD) so softmax uses exp2 directly.
// Q:(B,H,S,128); K:(B,G,S,128); Vt:(B,G,128,S). out = P·V * gate -> ctxg.
__global__ __launch_bounds__(512, 2) void k_flash2(
    const bf16* __restrict__ Q, const bf16* __restrict__ Kb,
    const bf16* __restrict__ Vt, const bf16* __restrict__ gate, int ldg,
    bf16* __restrict__ outc, int ldo) {
  __shared__ bf16 Ks[2][64 * 128];   // [kv][d], swizzled: byte ^= (kv&7)<<4
  __shared__ bf16 Vs[2][128 * 64];   // [d][kv], swizzled: byte ^= (d&7)<<4
  __shared__ bf16 Ps[8][32 * 72];    // per-wave P tile, pitch 72 bf16 = 144B
  const int tid = threadIdx.x, w = tid >> 6, lane = tid & 63;
  const int l16 = lane & 15, lh = lane >> 4;
  const int bh = blockIdx.x & 63;
  const int qi = blockIdx.x >> 6;       // 0..7, heavy chunks first
  const int qc = 7 - qi;
  const int h = bh & 15, b = bh >> 4, g = h >> 2;
  const int qbase = qc * 256;
  const int q0w = qbase + w * 32;
  const bf16* qp = Q + (((long long)b * H + h) * S + q0w) * HD;
  const bf16* kp = Kb + ((long long)b * G + g) * S * HD;
  const bf16* vp = Vt + ((long long)b * G + g) * (long long)HD * S;

  // Q fragments: aq[m][ks] = Q[q0w + m*16 + l16][ks*32 + lh*8 ..]
  bf16x8 aq[2][4];
#pragma unroll
  for (int m = 0; m < 2; ++m)
#pragma unroll
    for (int ks = 0; ks < 4; ++ks)
      aq[m][ks] = *(const bf16x8*)(qp + (long long)(m * 16 + l16) * HD + ks * 32 + lh * 8);

  f32x4 acc[2][8] = {};
  float mrow[2][4], lrow[2][4];
#pragma unroll
  for (int m = 0; m < 2; ++m)
#pragma unroll
    for (int r = 0; r < 4; ++r) { mrow[m][r] = -1e30f; lrow[m][r] = 0.f; }

  const int ntiles = qc * 4 + 4;

  auto stage = [&](int bi, int t) {
    const int kv0 = t << 6;
#pragma unroll
    for (int i = 0; i < 2; ++i) {
      int c = w * 128 + i * 64 + lane;
      int row = c >> 4;                                   // K: 16 chunks/row
      int cb = ((c & 15) << 4) ^ ((row & 7) << 4);
      gl_lds16(kp + (long long)(kv0 + row) * HD + (cb >> 1),
               (char*)Ks[bi] + (w * 128 + i * 64) * 16);
      int rowv = c >> 3;                                  // V^T: 8 chunks/row
      int cbv = ((c & 7) << 4) ^ ((rowv & 7) << 4);
      gl_lds16(vp + (long long)rowv * S + kv0 + (cbv >> 1),
               (char*)Vs[bi] + (w * 128 + i * 64) * 16);
    }
  };

  stage(0, 0);
  __syncthreads();

  for (int t = 0; t < ntiles; ++t) {
    const int buf = t & 1;
    if (t + 1 < ntiles) stage(buf ^ 1, t + 1);
    const int kv0 = t << 6;
    if (kv0 <= q0w + 31) {
      // ---- QK^T: S = Q K^T, 32 MFMAs ----
      f32x4 s[2][4] = {};
#pragma unroll
      for (int ks = 0; ks < 4; ++ks)
#pragma unroll
        for (int n = 0; n < 4; ++n) {
          int row = n * 16 + l16;
          int off = row * 256 + ((ks * 64 + lh * 16) ^ ((row & 7) << 4));
          bf16x8 kb = *(const bf16x8*)((const char*)Ks[buf] + off);
#pragma unroll
          for (int m = 0; m < 2; ++m) s[m][n] = mfma16(aq[m][ks], kb, s[m][n]);
        }
      // ---- causal mask ----
      if (kv0 + 63 > q0w) {
#pragma unroll
        for (int m = 0; m < 2; ++m)
#pragma unroll
          for (int n = 0; n < 4; ++n)
#pragma unroll
            for (int r = 0; r < 4; ++r) {
              int col = kv0 + n * 16 + l16;
              int rowg = q0w + m * 16 + lh * 4 + r;
              if (col > rowg) s[m][n][r] = -1e30f;
            }
      }
      // ---- online softmax (log2 domain; Q pre-scaled by L2E/sqrt(HD)) ----
      float pm[2][4];
#pragma unroll
      for (int m = 0; m < 2; ++m)
#pragma unroll
        for (int r = 0; r < 4; ++r)
          pm[m][r] = fmaxf(fmaxf(s[m][0][r], s[m][1][r]), fmaxf(s[m][2][r], s[m][3][r]));
#pragma unroll
      for (int st = 1; st < 16; st <<= 1)
#pragma unroll
        for (int m = 0; m < 2; ++m)
#pragma unroll
          for (int r = 0; r < 4; ++r) pm[m][r] = fmaxf(pm[m][r], __shfl_xor(pm[m][r], st));
      float resc[2][4];
#pragma unroll
      for (int m = 0; m < 2; ++m)
#pragma unroll
        for (int r = 0; r < 4; ++r) {
          float mn = fmaxf(mrow[m][r], pm[m][r]);
          resc[m][r] = exp2f(mrow[m][r] - mn);
          mrow[m][r] = mn;
        }
      // ---- P = exp2(S - m), write P tile, update l, rescale acc ----
#pragma unroll
      for (int m = 0; m < 2; ++m)
#pragma unroll
        for (int n = 0; n < 4; ++n) {
          float psum = 0.f;
#pragma unroll
          for (int r = 0; r < 4; ++r) {
            float p = exp2f(s[m][n][r] - mrow[m][r]);
            s[m][n][r] = p;
            Ps[w][(m * 16 + lh * 4 + r) * 72 + n * 16 + l16] = (bf16)p;
          }
        }
#pragma unroll
      for (int m = 0; m < 2; ++m)
#pragma unroll
        for (int r = 0; r < 4; ++r)
          lrow[m][r] = lrow[m][r] * resc[m][r] +
                       (s[m][0][r] + s[m][1][r] + s[m][2][r] + s[m][3][r]);
#pragma unroll
      for (int m = 0; m < 2; ++m)
#pragma unroll
        for (int dt = 0; dt < 8; ++dt)
#pragma unroll
          for (int r = 0; r < 4; ++r) acc[m][dt][r] *= resc[m][r];
      // ---- PV: acc += P V, 32 MFMAs ----
      bf16x8 pa[2][2];
#pragma unroll
      for (int m = 0; m < 2; ++m)
#pragma unroll
        for (int kf = 0; kf < 2; ++kf)
          pa[m][kf] = *(const bf16x8*)((const char*)&Ps[w][0] +
                                       (m * 16 + l16) * 144 + kf * 64 + lh * 16);
#pragma unroll
      for (int dt = 0; dt < 8; ++dt) {
        int d = dt * 16 + l16;
#pragma unroll
        for (int kf = 0; kf < 2; ++kf) {
          int off = d * 128 + ((kf * 64 + lh * 16) ^ ((d & 7) << 4));
          bf16x8 vb = *(const bf16x8*)((const char*)Vs[buf] + off);
#pragma unroll
          for (int m = 0; m < 2; ++m) acc[m][dt] = mfma16(pa[m][kf], vb, acc[m][dt]);
        }
      }
    }
    __syncthreads();  // drains vmcnt (staged tile t+1 ready) + lgkm
  }

  // ---- final: reduce l across the 16 column-lanes, normalize, gate, store ----
#pragma unroll
  for (int st = 1; st < 16; st <<= 1)
#pragma unroll
    for (int m = 0; m < 2; ++m)
#pragma unroll
      for (int r = 0; r < 4; ++r) lrow[m][r] += __shfl_xor(lrow[m][r], st);
  float inv[2][4];
#pragma unroll
  for (int m = 0; m < 2; ++m)
#pragma unroll
    for (int r = 0; r < 4; ++r) inv[m][r] = 1.f / lrow[m][r];
#pragma unroll
  for (int m = 0; m < 2; ++m)
#pragma unroll
    for (int dt = 0; dt < 8; ++dt)
#pragma unroll
      for (int r = 0; r < 4; ++r) {
        int rowg = q0w + m * 16 + lh * 4 + r;
        long long row = (long long)b * S + rowg;
        int col = h * HD + dt * 16 + l16;
        float gv = (float)gate[row * ldg + col];
        outc[row * ldo + col] = (bf16)(acc[m][dt][r] * inv[m][r] * gv);
      }
}

extern "C" void kernel_launch(void* const* d_in, const int* in_sizes, int n_in,
                              void* d_out, int out_size, void* d_ws, size_t ws_size,
                              hipStream_t stream) {
  const float* x = (const float*)d_in[0];
  const float* cosT = (const float*)d_in[2];
  const float* sinT = (const float*)d_in[3];
  const float* wq = (const float*)d_in[4];
  const float* wk = (const float*)d_in[5];
  const float* wv = (const float*)d_in[6];
  const float* wg = (const float*)d_in[7];
  const float* wo = (const float*)d_in[8];
  const float* qs = (const float*)d_in[9];
  const float* ksc = (const float*)d_in[10];
  float* out = (float*)d_out;
  char* ws = (char*)d_ws;

  if (ws_size < 146800640) return;
  bf16* xb = (bf16*)(ws);
  bf16* wcat = (bf16*)(ws + 33554432);
  bf16* woT = (bf16*)(ws + 54525952);
  bf16* C1 = (bf16*)(ws + 62914560);
  bf16* qbuf = xb;
  bf16* kbuf = wcat;
  bf16* vtbuf = wcat + 4194304;
  bf16* gatep = C1 + 3072;
  bf16* ctxg = C1;

  dim3 tb(32, 8);
  k_f32_to_bf16<<<8192, 256, 0, stream>>>(x, xb, Bb * S * Dd / 8);
  k_transpose_bf16<float><<<dim3(64, 64, 1), tb, 0, stream>>>(
      wq, 0, 1, 0, 2048, wcat, 0, 2048, 2048, 2048);
  k_transpose_bf16<float><<<dim3(16, 64, 1), tb, 0, stream>>>(
      wk, 0, 1, 0, 512, wcat + 2048 * 2048, 0, 2048, 2048, 512);
  k_transpose_bf16<float><<<dim3(16, 64, 1), tb, 0, stream>>>(
      wv, 0, 1, 0, 512, wcat + 2560 * 2048, 0, 2048, 2048, 512);
  k_transpose_bf16<float><<<dim3(64, 64, 1), tb, 0, stream>>>(
      wg, 0, 1, 0, 2048, wcat + 3072 * 2048, 0, 2048, 2048, 2048);
  k_transpose_bf16<float><<<dim3(64, 64, 1), tb, 0, stream>>>(
      wo, 0, 1, 0, 2048, woT, 0, 2048, 2048, 2048);
  // fused QKVG GEMM: (8192x2048) @ (2048x5120) -> C1 bf16
  k_gemm_bt<bf16><<<64 * 40, 256, 0, stream>>>(xb, 2048, wcat, 2048, C1, 5120,
                                               8192, 5120, 2048);
  // RMSNorm + RoPE; L2E/sqrt(128) folded into q so attention uses exp2
  k_rms_rope<<<32768, 256, 0, stream>>>(C1, 5120, 16, qs, cosT, sinT, qbuf,
                                        0.12751879523209308f, 131072);
  k_rms_rope<<<8192, 256, 0, stream>>>(C1 + 2048, 5120, 4, ksc, cosT, sinT, kbuf,
                                       1.0f, 32768);
  // V -> V^T (B,G,128,S)
  k_transpose_bf16<bf16><<<dim3(4, 64, 16), tb, 0, stream>>>(
      C1 + 2560, (long long)2048 * 5120, 4, 128, 5120, vtbuf,
      (long long)128 * 2048, 2048, 2048, 128);
  // gate = sigmoid(xwg) in-place
  k_sigmoid<<<8192, 256, 0, stream>>>(gatep, 5120, 256, 2097152);
  // flash attention v2 + gate -> C1 cols 0:2048
  k_flash2<<<512, 512, 0, stream>>>(qbuf, kbuf, vtbuf, gatep, 5120, ctxg, 5120);
  // output GEMM: (8192x2048) @ (2048x2048) -> out fp32
  k_gemm_bt<float><<<64 * 16, 256, 0, stream>>>(ctxg, 5120, woT, 2048, out, 2048,
                                                8192, 2048, 2048);
}

// Round 3
// 514.021 us; speedup vs baseline: 2.5408x; 1.1466x over previous
//
#include <hip/hip_runtime.h>

typedef __bf16 bf16;
typedef __attribute__((ext_vector_type(8))) __bf16 bf16x8;
typedef __attribute__((ext_vector_type(4))) float f32x4;

constexpr int Bb = 4, S = 2048, Dd = 2048, H = 16, G = 4, HD = 128;
constexpr float L2E = 1.4426950408889634f;

__device__ inline f32x4 mfma16(bf16x8 a, bf16x8 b, f32x4 c) {
  return __builtin_amdgcn_mfma_f32_16x16x32_bf16(a, b, c, 0, 0, 0);
}

__device__ inline void gl_lds16(const void* g, void* l) {
  __builtin_amdgcn_global_load_lds(
      (const __attribute__((address_space(1))) void*)g,
      (__attribute__((address_space(3))) void*)l, 16, 0, 0);
}

// ---------------- fp32 -> bf16 elementwise (vectorized) ----------------
__global__ __launch_bounds__(256) void k_f32_to_bf16(
    const float* __restrict__ in, bf16* __restrict__ out, int n8) {
  int i = blockIdx.x * 256 + threadIdx.x;
  if (i >= n8) return;
  const float4* p = (const float4*)(in + (long long)i * 8);
  float4 a = p[0], b = p[1];
  bf16x8 v;
  v[0] = (bf16)a.x; v[1] = (bf16)a.y; v[2] = (bf16)a.z; v[3] = (bf16)a.w;
  v[4] = (bf16)b.x; v[5] = (bf16)b.y; v[6] = (bf16)b.z; v[7] = (bf16)b.w;
  *(bf16x8*)(out + (long long)i * 8) = v;
}

// ---------------- transpose + convert to bf16 ----------------
template <typename InT>
__global__ __launch_bounds__(256) void k_transpose_bf16(
    const InT* __restrict__ in, long long s1, int nb2, long long s2, int ldin,
    bf16* __restrict__ out, long long obatch, int ldout, int R, int C) {
  __shared__ float tile[32][33];
  int z = blockIdx.z;
  const InT* ip = in + (long long)(z / nb2) * s1 + (long long)(z % nb2) * s2;
  bf16* op = out + (long long)z * obatch;
  int c0 = blockIdx.x * 32, r0 = blockIdx.y * 32;
  int tx = threadIdx.x, ty = threadIdx.y;
#pragma unroll
  for (int i = 0; i < 4; ++i) {
    int r = r0 + ty + i * 8, c = c0 + tx;
    tile[ty + i * 8][tx] = (r < R && c < C) ? (float)ip[(long long)r * ldin + c] : 0.f;
  }
  __syncthreads();
#pragma unroll
  for (int i = 0; i < 4; ++i) {
    int c = c0 + ty + i * 8, r = r0 + tx;
    if (c < C && r < R) op[(long long)c * ldout + r] = (bf16)tile[tx][ty + i * 8];
  }
}

// ---------------- 256x256 8-phase bf16 GEMM:  C = A(MxK) * Bt(NxK)^T -------
// 512 threads = 8 waves (2M x 4N), BK=64, dbuf LDS 128 KiB, row-XOR swizzle
// (linear gl_lds dest + pre-swizzled global source + swizzled ds_read).
// Counted vmcnt(4) at phases 1,2,4 (never 0); setprio around MFMA clusters.
template <typename CT>
__global__ __launch_bounds__(512, 2) void k_gemm256(
    const bf16* __restrict__ A, int lda, const bf16* __restrict__ Bt, int ldb,
    CT* __restrict__ C, int ldc, int M, int N, int K) {
  __shared__ bf16 ldsbuf[65536];  // 128 KB: [buf:64KB][A:32KB | B:32KB]
  char* lds2 = (char*)ldsbuf;
  const int tid = threadIdx.x;
  const int w = tid >> 6, lane = tid & 63;
  const int l16 = lane & 15, lh = lane >> 4;
  const int wr = w >> 2, wc = w & 3;
  // XCD-aware block swizzle (grid % 8 == 0 for our shapes)
  const int nbn = N >> 8;
  const int cpx = gridDim.x >> 3;
  const int swz = (blockIdx.x & 7) * cpx + (blockIdx.x >> 3);
  const int bm = swz / nbn, bn = swz % nbn;
  const int m0 = bm << 8, n0 = bn << 8;

  // staging geometry: each gl_lds covers 8 rows x 128B; lane l -> row +l/8,
  // source col pre-swizzled so linear LDS write == swizzled layout
  const int lrow = lane >> 3;
  const int lcol = ((lane & 7) ^ lrow) * 8;  // element column
  const int arb = wr * 128 + wc * 16;        // A rows: this wave's stage base
  const int xg = wc >> 1, sg = wr * 2 + (wc & 1);
  const int brb = xg * 128 + (sg >> 1) * 64 + (sg & 1) * 16;  // B stage base
  const bf16* aS0 = A + (long long)(m0 + arb + lrow) * lda + lcol;
  const bf16* aS1 = A + (long long)(m0 + arb + 8 + lrow) * lda + lcol;
  const bf16* bS0 = Bt + (long long)(n0 + brb + lrow) * ldb + lcol;
  const bf16* bS1 = Bt + (long long)(n0 + brb + 8 + lrow) * ldb + lcol;

  auto stageA = [&](int buf, int k0, int hi) {
    gl_lds16(aS0 + (long long)hi * 64 * lda + k0,
             lds2 + buf * 65536 + (arb + hi * 64) * 128);
    gl_lds16(aS1 + (long long)hi * 64 * lda + k0,
             lds2 + buf * 65536 + (arb + hi * 64 + 8) * 128);
  };
  auto stageB = [&](int buf, int k0, int hi) {
    gl_lds16(bS0 + (long long)hi * 32 * ldb + k0,
             lds2 + buf * 65536 + 32768 + (brb + hi * 32) * 128);
    gl_lds16(bS1 + (long long)hi * 32 * ldb + k0,
             lds2 + buf * 65536 + 32768 + (brb + hi * 32 + 8) * 128);
  };

  f32x4 acc[8][4] = {};
  const int NT = K >> 6;

  // prologue: stage tile 0 in steady-state order (Alo, Bn0, Bn1, Ahi)
  stageA(0, 0, 0);
  stageB(0, 0, 0);
  stageB(0, 0, 1);
  stageA(0, 0, 1);
  asm volatile("s_waitcnt vmcnt(4)" ::: "memory");  // Alo+Bn0 resident
  __builtin_amdgcn_s_barrier();

  const int swzc = (l16 & 7) << 4;
  for (int t = 0; t < NT; ++t) {
    const int buf = t & 1, nb = buf ^ 1;
    const int kn = (t + 1) << 6;
    const bool more = (t + 1 < NT);
    const char* La = lds2 + buf * 65536;
    const char* Lb = La + 32768;
    bf16x8 af[4][2], bn0[2][2], bn1[2][2];
    // ======== phase 1: quadrant (m0-3, n0-1) ========
    if (more) stageA(nb, kn, 0);
#pragma unroll
    for (int m = 0; m < 4; ++m)
#pragma unroll
      for (int ks = 0; ks < 2; ++ks)
        af[m][ks] = *(const bf16x8*)(La + (wr * 128 + m * 16 + l16) * 128 +
                                     ((ks * 64 + lh * 16) ^ swzc));
#pragma unroll
    for (int n = 0; n < 2; ++n)
#pragma unroll
      for (int ks = 0; ks < 2; ++ks)
        bn0[n][ks] = *(const bf16x8*)(Lb + (wc * 64 + n * 16 + l16) * 128 +
                                      ((ks * 64 + lh * 16) ^ swzc));
    __builtin_amdgcn_s_barrier();
    asm volatile("s_waitcnt lgkmcnt(0)" ::: "memory");
    __builtin_amdgcn_sched_barrier(0);
    __builtin_amdgcn_s_setprio(1);
#pragma unroll
    for (int m = 0; m < 4; ++m)
#pragma unroll
      for (int n = 0; n < 2; ++n)
#pragma unroll
        for (int ks = 0; ks < 2; ++ks)
          acc[m][n] = mfma16(af[m][ks], bn0[n][ks], acc[m][n]);
    __builtin_amdgcn_s_setprio(0);
    asm volatile("s_waitcnt vmcnt(4)" ::: "memory");
    __builtin_amdgcn_s_barrier();
    // ======== phase 2: quadrant (m0-3, n2-3) ========
    if (more) stageB(nb, kn, 0);
#pragma unroll
    for (int n = 0; n < 2; ++n)
#pragma unroll
      for (int ks = 0; ks < 2; ++ks)
        bn1[n][ks] = *(const bf16x8*)(Lb + (wc * 64 + 32 + n * 16 + l16) * 128 +
                                      ((ks * 64 + lh * 16) ^ swzc));
    __builtin_amdgcn_s_barrier();
    asm volatile("s_waitcnt lgkmcnt(0)" ::: "memory");
    __builtin_amdgcn_sched_barrier(0);
    __builtin_amdgcn_s_setprio(1);
#pragma unroll
    for (int m = 0; m < 4; ++m)
#pragma unroll
      for (int n = 0; n < 2; ++n)
#pragma unroll
        for (int ks = 0; ks < 2; ++ks)
          acc[m][2 + n] = mfma16(af[m][ks], bn1[n][ks], acc[m][2 + n]);
    __builtin_amdgcn_s_setprio(0);
    asm volatile("s_waitcnt vmcnt(4)" ::: "memory");
    __builtin_amdgcn_s_barrier();
    // ======== phase 3: quadrant (m4-7, n2-3) ========
    if (more) stageB(nb, kn, 1);
#pragma unroll
    for (int m = 0; m < 4; ++m)
#pragma unroll
      for (int ks = 0; ks < 2; ++ks)
        af[m][ks] = *(const bf16x8*)(La + (wr * 128 + 64 + m * 16 + l16) * 128 +
                                     ((ks * 64 + lh * 16) ^ swzc));
    __builtin_amdgcn_s_barrier();
    asm volatile("s_waitcnt lgkmcnt(0)" ::: "memory");
    __builtin_amdgcn_sched_barrier(0);
    __builtin_amdgcn_s_setprio(1);
#pragma unroll
    for (int m = 0; m < 4; ++m)
#pragma unroll
      for (int n = 0; n < 2; ++n)
#pragma unroll
        for (int ks = 0; ks < 2; ++ks)
          acc[4 + m][2 + n] = mfma16(af[m][ks], bn1[n][ks], acc[4 + m][2 + n]);
    __builtin_amdgcn_s_setprio(0);
    __builtin_amdgcn_s_barrier();
    // ======== phase 4: quadrant (m4-7, n0-1), no new ds_reads ========
    if (more) stageA(nb, kn, 1);
    __builtin_amdgcn_s_barrier();
    __builtin_amdgcn_s_setprio(1);
#pragma unroll
    for (int m = 0; m < 4; ++m)
#pragma unroll
      for (int n = 0; n < 2; ++n)
#pragma unroll
        for (int ks = 0; ks < 2; ++ks)
          acc[4 + m][n] = mfma16(af[m][ks], bn0[n][ks], acc[4 + m][n]);
    __builtin_amdgcn_s_setprio(0);
    asm volatile("s_waitcnt vmcnt(4)" ::: "memory");
    __builtin_amdgcn_s_barrier();
  }

#pragma unroll
  for (int m = 0; m < 8; ++m)
#pragma unroll
    for (int n = 0; n < 4; ++n)
#pragma unroll
      for (int r = 0; r < 4; ++r)
        C[(long long)(m0 + wr * 128 + m * 16 + lh * 4 + r) * ldc + n0 + wc * 64 +
          n * 16 + l16] = (CT)acc[m][n][r];
}

// ---------------- RMSNorm + RoPE (wave per (b,s,h) row) ----------------
__global__ __launch_bounds__(256) void k_rms_rope(
    const bf16* __restrict__ in, int ldin, int nh, const float* __restrict__ scale,
    const float* __restrict__ cosT, const float* __restrict__ sinT,
    bf16* __restrict__ out, float oscale, int nwaves) {
  int wid = (blockIdx.x * 256 + threadIdx.x) >> 6;
  if (wid >= nwaves) return;
  int lane = threadIdx.x & 63;
  int h = wid % nh;
  int bs = wid / nh;
  int s = bs % S;
  int b = bs / S;
  const bf16* ip = in + (long long)bs * ldin + h * HD;
  float x1 = (float)ip[lane], x2 = (float)ip[lane + 64];
  float ss = x1 * x1 + x2 * x2;
#pragma unroll
  for (int m = 1; m < 64; m <<= 1) ss += __shfl_xor(ss, m);
  float rms = rsqrtf(ss * (1.f / 128.f) + 1e-6f);
  float n1 = x1 * rms * (1.f + scale[lane]);
  float n2 = x2 * rms * (1.f + scale[lane + 64]);
  float o1 = (n1 * cosT[s * 128 + lane] - n2 * sinT[s * 128 + lane]) * oscale;
  float o2 = (n2 * cosT[s * 128 + lane + 64] + n1 * sinT[s * 128 + lane + 64]) * oscale;
  bf16* op = out + (((long long)b * nh + h) * S + s) * HD;
  op[lane] = (bf16)o1;
  op[lane + 64] = (bf16)o2;
}

// ---------------- sigmoid in-place on strided bf16 slice ----------------
__global__ __launch_bounds__(256) void k_sigmoid(bf16* __restrict__ p, int ld,
                                                 int cols8, int n) {
  int i = blockIdx.x * 256 + threadIdx.x;
  if (i >= n) return;
  int row = i / cols8, c = (i % cols8) * 8;
  bf16x8* q = (bf16x8*)(p + (long long)row * ld + c);
  bf16x8 v = *q;
#pragma unroll
  for (int j = 0; j < 8; ++j) {
    float f = (float)v[j];
    v[j] = (bf16)(1.f / (1.f + exp2f(-f * L2E)));
  }
  *q = v;
}

// ---------------- causal GQA flash attention v2 ----------------
__global__ __launch_bounds__(512, 2) void k_flash2(
    const bf16* __restrict__ Q, const bf16* __restrict__ Kb,
    const bf16* __restrict__ Vt, const bf16* __restrict__ gate, int ldg,
    bf16* __restrict__ outc, int ldo) {
  __shared__ bf16 Ks[2][64 * 128];   // [kv][d], swizzled: byte ^= (kv&7)<<4
  __shared__ bf16 Vs[2][128 * 64];   // [d][kv], swizzled: byte ^= (d&7)<<4
  __shared__ bf16 Ps[8][32 * 72];
  const int tid = threadIdx.x, w = tid >> 6, lane = tid & 63;
  const int l16 = lane & 15, lh = lane >> 4;
  const int bh = blockIdx.x & 63;
  const int qi = blockIdx.x >> 6;
  const int qc = 7 - qi;
  const int h = bh & 15, b = bh >> 4, g = h >> 2;
  const int qbase = qc * 256;
  const int q0w = qbase + w * 32;
  const bf16* qp = Q + (((long long)b * H + h) * S + q0w) * HD;
  const bf16* kp = Kb + ((long long)b * G + g) * S * HD;
  const bf16* vp = Vt + ((long long)b * G + g) * (long long)HD * S;

  bf16x8 aq[2][4];
#pragma unroll
  for (int m = 0; m < 2; ++m)
#pragma unroll
    for (int ks = 0; ks < 4; ++ks)
      aq[m][ks] = *(const bf16x8*)(qp + (long long)(m * 16 + l16) * HD + ks * 32 + lh * 8);

  f32x4 acc[2][8] = {};
  float mrow[2][4], lrow[2][4];
#pragma unroll
  for (int m = 0; m < 2; ++m)
#pragma unroll
    for (int r = 0; r < 4; ++r) { mrow[m][r] = -1e30f; lrow[m][r] = 0.f; }

  const int ntiles = qc * 4 + 4;

  auto stage = [&](int bi, int t) {
    const int kv0 = t << 6;
#pragma unroll
    for (int i = 0; i < 2; ++i) {
      int c = w * 128 + i * 64 + lane;
      int row = c >> 4;
      int cb = ((c & 15) << 4) ^ ((row & 7) << 4);
      gl_lds16(kp + (long long)(kv0 + row) * HD + (cb >> 1),
               (char*)Ks[bi] + (w * 128 + i * 64) * 16);
      int rowv = c >> 3;
      int cbv = ((c & 7) << 4) ^ ((rowv & 7) << 4);
      gl_lds16(vp + (long long)rowv * S + kv0 + (cbv >> 1),
               (char*)Vs[bi] + (w * 128 + i * 64) * 16);
    }
  };

  stage(0, 0);
  __syncthreads();

  for (int t = 0; t < ntiles; ++t) {
    const int buf = t & 1;
    if (t + 1 < ntiles) stage(buf ^ 1, t + 1);
    const int kv0 = t << 6;
    if (kv0 <= q0w + 31) {
      f32x4 s[2][4] = {};
#pragma unroll
      for (int ks = 0; ks < 4; ++ks)
#pragma unroll
        for (int n = 0; n < 4; ++n) {
          int row = n * 16 + l16;
          int off = row * 256 + ((ks * 64 + lh * 16) ^ ((row & 7) << 4));
          bf16x8 kb = *(const bf16x8*)((const char*)Ks[buf] + off);
#pragma unroll
          for (int m = 0; m < 2; ++m) s[m][n] = mfma16(aq[m][ks], kb, s[m][n]);
        }
      if (kv0 + 63 > q0w) {
#pragma unroll
        for (int m = 0; m < 2; ++m)
#pragma unroll
          for (int n = 0; n < 4; ++n)
#pragma unroll
            for (int r = 0; r < 4; ++r) {
              int col = kv0 + n * 16 + l16;
              int rowg = q0w + m * 16 + lh * 4 + r;
              if (col > rowg) s[m][n][r] = -1e30f;
            }
      }
      float pm[2][4];
#pragma unroll
      for (int m = 0; m < 2; ++m)
#pragma unroll
        for (int r = 0; r < 4; ++r)
          pm[m][r] = fmaxf(fmaxf(s[m][0][r], s[m][1][r]), fmaxf(s[m][2][r], s[m][3][r]));
#pragma unroll
      for (int st = 1; st < 16; st <<= 1)
#pragma unroll
        for (int m = 0; m < 2; ++m)
#pragma unroll
          for (int r = 0; r < 4; ++r) pm[m][r] = fmaxf(pm[m][r], __shfl_xor(pm[m][r], st));
      float resc[2][4];
#pragma unroll
      for (int m = 0; m < 2; ++m)
#pragma unroll
        for (int r = 0; r < 4; ++r) {
          float mn = fmaxf(mrow[m][r], pm[m][r]);
          resc[m][r] = exp2f(mrow[m][r] - mn);
          mrow[m][r] = mn;
        }
#pragma unroll
      for (int m = 0; m < 2; ++m)
#pragma unroll
        for (int n = 0; n < 4; ++n) {
#pragma unroll
          for (int r = 0; r < 4; ++r) {
            float p = exp2f(s[m][n][r] - mrow[m][r]);
            s[m][n][r] = p;
            Ps[w][(m * 16 + lh * 4 + r) * 72 + n * 16 + l16] = (bf16)p;
          }
        }
#pragma unroll
      for (int m = 0; m < 2; ++m)
#pragma unroll
        for (int r = 0; r < 4; ++r)
          lrow[m][r] = lrow[m][r] * resc[m][r] +
                       (s[m][0][r] + s[m][1][r] + s[m][2][r] + s[m][3][r]);
#pragma unroll
      for (int m = 0; m < 2; ++m)
#pragma unroll
        for (int dt = 0; dt < 8; ++dt)
#pragma unroll
          for (int r = 0; r < 4; ++r) acc[m][dt][r] *= resc[m][r];
      bf16x8 pa[2][2];
#pragma unroll
      for (int m = 0; m < 2; ++m)
#pragma unroll
        for (int kf = 0; kf < 2; ++kf)
          pa[m][kf] = *(const bf16x8*)((const char*)&Ps[w][0] +
                                       (m * 16 + l16) * 144 + kf * 64 + lh * 16);
#pragma unroll
      for (int dt = 0; dt < 8; ++dt) {
        int d = dt * 16 + l16;
#pragma unroll
        for (int kf = 0; kf < 2; ++kf) {
          int off = d * 128 + ((kf * 64 + lh * 16) ^ ((d & 7) << 4));
          bf16x8 vb = *(const bf16x8*)((const char*)Vs[buf] + off);
#pragma unroll
          for (int m = 0; m < 2; ++m) acc[m][dt] = mfma16(pa[m][kf], vb, acc[m][dt]);
        }
      }
    }
    __syncthreads();
  }

#pragma unroll
  for (int st = 1; st < 16; st <<= 1)
#pragma unroll
    for (int m = 0; m < 2; ++m)
#pragma unroll
      for (int r = 0; r < 4; ++r) lrow[m][r] += __shfl_xor(lrow[m][r], st);
  float inv[2][4];
#pragma unroll
  for (int m = 0; m < 2; ++m)
#pragma unroll
    for (int r = 0; r < 4; ++r) inv[m][r] = 1.f / lrow[m][r];
#pragma unroll
  for (int m = 0; m < 2; ++m)
#pragma unroll
    for (int dt = 0; dt < 8; ++dt)
#pragma unroll
      for (int r = 0; r < 4; ++r) {
        int rowg = q0w + m * 16 + lh * 4 + r;
        long long row = (long long)b * S + rowg;
        int col = h * HD + dt * 16 + l16;
        float gv = (float)gate[row * ldg + col];
        outc[row * ldo + col] = (bf16)(acc[m][dt][r] * inv[m][r] * gv);
      }
}

extern "C" void kernel_launch(void* const* d_in, const int* in_sizes, int n_in,
                              void* d_out, int out_size, void* d_ws, size_t ws_size,
                              hipStream_t stream) {
  const float* x = (const float*)d_in[0];
  const float* cosT = (const float*)d_in[2];
  const float* sinT = (const float*)d_in[3];
  const float* wq = (const float*)d_in[4];
  const float* wk = (const float*)d_in[5];
  const float* wv = (const float*)d_in[6];
  const float* wg = (const float*)d_in[7];
  const float* wo = (const float*)d_in[8];
  const float* qs = (const float*)d_in[9];
  const float* ksc = (const float*)d_in[10];
  float* out = (float*)d_out;
  char* ws = (char*)d_ws;

  if (ws_size < 146800640) return;
  bf16* xb = (bf16*)(ws);
  bf16* wcat = (bf16*)(ws + 33554432);
  bf16* woT = (bf16*)(ws + 54525952);
  bf16* C1 = (bf16*)(ws + 62914560);
  bf16* qbuf = xb;
  bf16* kbuf = wcat;
  bf16* vtbuf = wcat + 4194304;
  bf16* gatep = C1 + 3072;
  bf16* ctxg = C1;

  dim3 tb(32, 8);
  k_f32_to_bf16<<<8192, 256, 0, stream>>>(x, xb, Bb * S * Dd / 8);
  k_transpose_bf16<float><<<dim3(64, 64, 1), tb, 0, stream>>>(
      wq, 0, 1, 0, 2048, wcat, 0, 2048, 2048, 2048);
  k_transpose_bf16<float><<<dim3(16, 64, 1), tb, 0, stream>>>(
      wk, 0, 1, 0, 512, wcat + 2048 * 2048, 0, 2048, 2048, 512);
  k_transpose_bf16<float><<<dim3(16, 64, 1), tb, 0, stream>>>(
      wv, 0, 1, 0, 512, wcat + 2560 * 2048, 0, 2048, 2048, 512);
  k_transpose_bf16<float><<<dim3(64, 64, 1), tb, 0, stream>>>(
      wg, 0, 1, 0, 2048, wcat + 3072 * 2048, 0, 2048, 2048, 2048);
  k_transpose_bf16<float><<<dim3(64, 64, 1), tb, 0, stream>>>(
      wo, 0, 1, 0, 2048, woT, 0, 2048, 2048, 2048);
  // fused QKVG GEMM: (8192x2048) @ (2048x5120) -> C1 bf16 [8-phase 256^2]
  k_gemm256<bf16><<<32 * 20, 512, 0, stream>>>(xb, 2048, wcat, 2048, C1, 5120,
                                               8192, 5120, 2048);
  // RMSNorm + RoPE; L2E/sqrt(128) folded into q so attention uses exp2
  k_rms_rope<<<32768, 256, 0, stream>>>(C1, 5120, 16, qs, cosT, sinT, qbuf,
                                        0.12751879523209308f, 131072);
  k_rms_rope<<<8192, 256, 0, stream>>>(C1 + 2048, 5120, 4, ksc, cosT, sinT, kbuf,
                                       1.0f, 32768);
  // V -> V^T (B,G,128,S)
  k_transpose_bf16<bf16><<<dim3(4, 64, 16), tb, 0, stream>>>(
      C1 + 2560, (long long)2048 * 5120, 4, 128, 5120, vtbuf,
      (long long)128 * 2048, 2048, 2048, 128);
  // gate = sigmoid(xwg) in-place
  k_sigmoid<<<8192, 256, 0, stream>>>(gatep, 5120, 256, 2097152);
  // flash attention v2 + gate -> C1 cols 0:2048
  k_flash2<<<512, 512, 0, stream>>>(qbuf, kbuf, vtbuf, gatep, 5120, ctxg, 5120);
  // output GEMM: (8192x2048) @ (2048x2048) -> out fp32 [8-phase 256^2]
  k_gemm256<float><<<32 * 8, 512, 0, stream>>>(ctxg, 5120, woT, 2048, out, 2048,
                                               8192, 2048, 2048);
}